// Round 3
// baseline (820.152 us; speedup 1.0000x reference)
//
#include <hip/hip_runtime.h>

#define DIN 256
#define DH  128
#define DE  64

typedef __attribute__((ext_vector_type(8))) short short8;
typedef __attribute__((ext_vector_type(4))) float f32x4;

__device__ inline unsigned short f2bf(float f) {
    unsigned u = __float_as_uint(f);
    return (unsigned short)((u + 0x7FFFu + ((u >> 16) & 1u)) >> 16);
}
__device__ inline float bf2f(unsigned short h) {
    return __uint_as_float((unsigned)h << 16);
}

// ---------------------------------------------------------------- CSR build

__global__ void init_counts_kernel(int* __restrict__ counts, int n) {
    int i = blockIdx.x * blockDim.x + threadIdx.x;
    if (i < n) counts[i] = 0;
}

__global__ void count_edges_kernel(const int* __restrict__ dst,
                                   int* __restrict__ counts, int E) {
    int e = blockIdx.x * blockDim.x + threadIdx.x;
    if (e < E) atomicAdd(&counts[dst[e]], 1);
}

__global__ void dinv_kernel(const int* __restrict__ counts,
                            float* __restrict__ dinv, int n) {
    int i = blockIdx.x * blockDim.x + threadIdx.x;
    if (i < n) dinv[i] = rsqrtf((float)counts[i] + 1.0f);
}

// block of 256 threads scans 1024 elements (4/thread)
__global__ void scan1_kernel(const int* __restrict__ counts,
                             int* __restrict__ rowptr,
                             int* __restrict__ blocksums, int n) {
    __shared__ int sd[256];
    int t = threadIdx.x;
    int base = blockIdx.x * 1024 + t * 4;
    int v[4];
#pragma unroll
    for (int i = 0; i < 4; i++) v[i] = (base + i < n) ? counts[base + i] : 0;
    int tsum = v[0] + v[1] + v[2] + v[3];
    sd[t] = tsum;
    __syncthreads();
    for (int off = 1; off < 256; off <<= 1) {
        int x = (t >= off) ? sd[t - off] : 0;
        __syncthreads();
        sd[t] += x;
        __syncthreads();
    }
    int p = sd[t] - tsum;  // exclusive prefix of this thread
#pragma unroll
    for (int i = 0; i < 4; i++) {
        if (base + i < n) rowptr[base + i] = p;
        p += v[i];
    }
    if (t == 255) blocksums[blockIdx.x] = sd[255];
}

__global__ void scan2_kernel(int* __restrict__ blocksums, int nb) {
    if (threadIdx.x == 0 && blockIdx.x == 0) {
        int run = 0;
        for (int i = 0; i < nb; i++) {
            int x = blocksums[i];
            blocksums[i] = run;
            run += x;
        }
    }
}

__global__ void scan3_kernel(int* __restrict__ rowptr, int* __restrict__ cursor,
                             const int* __restrict__ blocksums, int n, int E) {
    int i = blockIdx.x * blockDim.x + threadIdx.x;
    if (i < n) {
        int r = rowptr[i] + blocksums[i >> 10];
        rowptr[i] = r;
        cursor[i] = r;
    }
    if (i == 0) rowptr[n] = E;
}

__global__ void fill_csr_kernel(const int* __restrict__ src,
                                const int* __restrict__ dst,
                                const float* __restrict__ dinv,
                                int* __restrict__ cursor,
                                int* __restrict__ csr_src,
                                float* __restrict__ csr_coef, int E) {
    int e = blockIdx.x * blockDim.x + threadIdx.x;
    if (e >= E) return;
    int s = src[e], d = dst[e];
    int pos = atomicAdd(&cursor[d], 1);
    csr_src[pos] = s;
    csr_coef[pos] = dinv[s] * dinv[d];
}

// ---------------------------------------------------- weight transpose+split
// W[K][N] fp32  ->  Wh[N][K], Wl[N][K] bf16 (hi + residual-lo)

__global__ void wsplit_kernel(const float* __restrict__ W,
                              unsigned short* __restrict__ Wh,
                              unsigned short* __restrict__ Wl, int K, int N) {
    int i = blockIdx.x * blockDim.x + threadIdx.x;
    if (i >= K * N) return;
    int k = i / N, n = i % N;
    float v = W[i];
    unsigned short h = f2bf(v);
    Wh[(size_t)n * K + k] = h;
    Wl[(size_t)n * K + k] = f2bf(v - bf2f(h));
}

// ------------------------------------------------------- MFMA bf16x3 GEMM
// C[M,N] = A[M,K] * W[K,N] (+bias)(+relu), N = NF*16, K % 32 == 0.
// Block = 4 waves, each wave owns 16 rows x N cols. No LDS, no barriers.
// A fp32 from global, split hi/lo in-register; W pre-split bf16 [n][k].
// mfma_f32_16x16x32_bf16 layouts: A: row=l&15, k=8*(l>>4)+e;
// B: col=l&15, k=8*(l>>4)+e; D: col=l&15, row=4*(l>>4)+e (m89-verified).

template <int K, int NF, bool RELU, bool BIAS>
__global__ __launch_bounds__(256) void mfma_gemm(
    const float* __restrict__ A, const unsigned short* __restrict__ Wh,
    const unsigned short* __restrict__ Wl, const float* __restrict__ bias,
    float* __restrict__ C, int M) {
    constexpr int N = NF * 16;
    int tid = threadIdx.x;
    int wid = tid >> 6;
    int l = tid & 63;
    int lr = l & 15, lk = l >> 4;
    int row0 = (blockIdx.x * 4 + wid) * 16;
    int arow = row0 + lr;
    const float* ap = A + (size_t)(arow < M ? arow : 0) * K + lk * 8;
    const unsigned short* bhp = Wh + (size_t)lr * K + lk * 8;
    const unsigned short* blp = Wl + (size_t)lr * K + lk * 8;

    f32x4 acc[NF];
#pragma unroll
    for (int j = 0; j < NF; j++) acc[j] = (f32x4){0.f, 0.f, 0.f, 0.f};

    for (int k0 = 0; k0 < K; k0 += 32) {
        float4 a0 = *(const float4*)(ap + k0);
        float4 a1 = *(const float4*)(ap + k0 + 4);
        float av[8] = {a0.x, a0.y, a0.z, a0.w, a1.x, a1.y, a1.z, a1.w};
        short8 ah, al;
#pragma unroll
        for (int e = 0; e < 8; e++) {
            unsigned short h = f2bf(av[e]);
            ah[e] = (short)h;
            al[e] = (short)f2bf(av[e] - bf2f(h));
        }
#pragma unroll
        for (int j = 0; j < NF; j++) {
            short8 bh = *(const short8*)(bhp + (size_t)j * 16 * K + k0);
            short8 bl = *(const short8*)(blp + (size_t)j * 16 * K + k0);
            acc[j] = __builtin_amdgcn_mfma_f32_16x16x32_bf16(ah, bh, acc[j],
                                                             0, 0, 0);
            acc[j] = __builtin_amdgcn_mfma_f32_16x16x32_bf16(al, bh, acc[j],
                                                             0, 0, 0);
            acc[j] = __builtin_amdgcn_mfma_f32_16x16x32_bf16(ah, bl, acc[j],
                                                             0, 0, 0);
        }
    }

#pragma unroll
    for (int j = 0; j < NF; j++) {
        int col = j * 16 + lr;
        float bb = BIAS ? bias[col] : 0.f;
#pragma unroll
        for (int e = 0; e < 4; e++) {
            int r = row0 + lk * 4 + e;
            if (r < M) {
                float v = acc[j][e] + bb;
                if (RELU) v = fmaxf(v, 0.f);
                C[(size_t)r * N + col] = v;
            }
        }
    }
}

// ------------------------------------------------------------- aggregation
// out[v] = sum_{e: dst==v} h[src_e]*coef_e + h[v]*dinv[v]^2 + bias (, relu)
// float4/lane, D/4 lanes per node, 2-edge unroll with dual accumulators.

template <int D, bool RELU>
__global__ __launch_bounds__(256) void agg_kernel(
    const float* __restrict__ h, const float* __restrict__ dinv,
    const int* __restrict__ rowptr, const int* __restrict__ csr_src,
    const float* __restrict__ csr_coef, const float* __restrict__ bias,
    float* __restrict__ out, int n) {
    constexpr int TPN = D / 4;          // threads per node
    constexpr int NPB = 256 / TPN;      // nodes per block
    int v = blockIdx.x * NPB + threadIdx.x / TPN;
    int d4 = (threadIdx.x % TPN) * 4;
    if (v >= n) return;

    float di = dinv[v];
    float s2 = di * di;
    float4 hv = *(const float4*)&h[(size_t)v * D + d4];
    float4 bv = *(const float4*)&bias[d4];
    float4 acc0, acc1;
    acc0.x = fmaf(hv.x, s2, bv.x);
    acc0.y = fmaf(hv.y, s2, bv.y);
    acc0.z = fmaf(hv.z, s2, bv.z);
    acc0.w = fmaf(hv.w, s2, bv.w);
    acc1 = make_float4(0.f, 0.f, 0.f, 0.f);

    int e0 = rowptr[v], e1 = rowptr[v + 1];
    int e = e0;
    for (; e + 2 <= e1; e += 2) {
        int s0 = csr_src[e];
        int s1 = csr_src[e + 1];
        float c0 = csr_coef[e];
        float c1 = csr_coef[e + 1];
        float4 g0 = *(const float4*)&h[(size_t)s0 * D + d4];
        float4 g1 = *(const float4*)&h[(size_t)s1 * D + d4];
        acc0.x = fmaf(g0.x, c0, acc0.x);
        acc0.y = fmaf(g0.y, c0, acc0.y);
        acc0.z = fmaf(g0.z, c0, acc0.z);
        acc0.w = fmaf(g0.w, c0, acc0.w);
        acc1.x = fmaf(g1.x, c1, acc1.x);
        acc1.y = fmaf(g1.y, c1, acc1.y);
        acc1.z = fmaf(g1.z, c1, acc1.z);
        acc1.w = fmaf(g1.w, c1, acc1.w);
    }
    if (e < e1) {
        int s0 = csr_src[e];
        float c0 = csr_coef[e];
        float4 g0 = *(const float4*)&h[(size_t)s0 * D + d4];
        acc0.x = fmaf(g0.x, c0, acc0.x);
        acc0.y = fmaf(g0.y, c0, acc0.y);
        acc0.z = fmaf(g0.z, c0, acc0.z);
        acc0.w = fmaf(g0.w, c0, acc0.w);
    }
    float4 r;
    r.x = acc0.x + acc1.x;
    r.y = acc0.y + acc1.y;
    r.z = acc0.z + acc1.z;
    r.w = acc0.w + acc1.w;
    if (RELU) {
        r.x = fmaxf(r.x, 0.f);
        r.y = fmaxf(r.y, 0.f);
        r.z = fmaxf(r.z, 0.f);
        r.w = fmaxf(r.w, 0.f);
    }
    *(float4*)&out[(size_t)v * D + d4] = r;
}

// ---------------------------------------------------------------- launcher

extern "C" void kernel_launch(void* const* d_in, const int* in_sizes, int n_in,
                              void* d_out, int out_size, void* d_ws,
                              size_t ws_size, hipStream_t stream) {
    const float* x   = (const float*)d_in[0];
    const int*   ei  = (const int*)d_in[1];
    const float* W1  = (const float*)d_in[2];
    const float* b1  = (const float*)d_in[3];
    const float* W2  = (const float*)d_in[4];
    const float* b2  = (const float*)d_in[5];
    const float* W3  = (const float*)d_in[6];
    const float* b3  = (const float*)d_in[7];
    const float* Wd1 = (const float*)d_in[8];
    const float* bd1 = (const float*)d_in[9];
    const float* Wd2 = (const float*)d_in[10];
    const float* bd2 = (const float*)d_in[11];

    const int N = in_sizes[0] / DIN;
    const int E = in_sizes[1] / 2;
    const int* src = ei;
    const int* dst = ei + E;

    char* w = (char*)d_ws;
    auto alloc = [&](size_t bytes) -> char* {
        char* p = w;
        w += (bytes + 255) & ~(size_t)255;
        return p;
    };
    int*   counts    = (int*)alloc((size_t)N * 4);
    float* dinv      = (float*)alloc((size_t)N * 4);
    int*   rowptr    = (int*)alloc((size_t)(N + 1) * 4);
    int*   cursor    = (int*)alloc((size_t)N * 4);
    int*   blocksums = (int*)alloc(4096);
    int*   csr_src   = (int*)alloc((size_t)E * 4);
    float* csr_coef  = (float*)alloc((size_t)E * 4);
    float* Abuf      = (float*)alloc((size_t)N * DH * 4);
    unsigned short* W1h  = (unsigned short*)alloc(DIN * DH * 2);
    unsigned short* W1l  = (unsigned short*)alloc(DIN * DH * 2);
    unsigned short* W2h  = (unsigned short*)alloc(DH * DH * 2);
    unsigned short* W2l  = (unsigned short*)alloc(DH * DH * 2);
    unsigned short* W3h  = (unsigned short*)alloc(DH * DE * 2);
    unsigned short* W3l  = (unsigned short*)alloc(DH * DE * 2);
    unsigned short* Wd1h = (unsigned short*)alloc(DE * DH * 2);
    unsigned short* Wd1l = (unsigned short*)alloc(DE * DH * 2);
    unsigned short* Wd2h = (unsigned short*)alloc(DH * DIN * 2);
    unsigned short* Wd2l = (unsigned short*)alloc(DH * DIN * 2);

    float* zout = (float*)d_out;              // [N, 64]
    float* xhat = zout + (size_t)N * DE;      // [N, 256]
    float* S1   = xhat;                       // scratch (N*128 <= N*256)

    dim3 blk(256);
    int gN = (N + 255) / 256, gE = (E + 255) / 256;

    init_counts_kernel<<<gN, blk, 0, stream>>>(counts, N);
    count_edges_kernel<<<gE, blk, 0, stream>>>(dst, counts, E);
    dinv_kernel<<<gN, blk, 0, stream>>>(counts, dinv, N);
    int nb = (N + 1023) / 1024;
    scan1_kernel<<<nb, blk, 0, stream>>>(counts, rowptr, blocksums, N);
    scan2_kernel<<<1, 64, 0, stream>>>(blocksums, nb);
    scan3_kernel<<<gN, blk, 0, stream>>>(rowptr, cursor, blocksums, N, E);
    fill_csr_kernel<<<gE, blk, 0, stream>>>(src, dst, dinv, cursor, csr_src,
                                            csr_coef, E);

    // weight transpose + bf16 hi/lo split (tiny, once)
    wsplit_kernel<<<(DIN * DH + 255) / 256, blk, 0, stream>>>(W1, W1h, W1l,
                                                              DIN, DH);
    wsplit_kernel<<<(DH * DH + 255) / 256, blk, 0, stream>>>(W2, W2h, W2l,
                                                             DH, DH);
    wsplit_kernel<<<(DH * DE + 255) / 256, blk, 0, stream>>>(W3, W3h, W3l,
                                                             DH, DE);
    wsplit_kernel<<<(DE * DH + 255) / 256, blk, 0, stream>>>(Wd1, Wd1h, Wd1l,
                                                             DE, DH);
    wsplit_kernel<<<(DH * DIN + 255) / 256, blk, 0, stream>>>(Wd2, Wd2h, Wd2l,
                                                              DH, DIN);

    int gg = (N + 63) / 64;

    // h1 = relu(agg(x @ W1) + b1)
    mfma_gemm<DIN, DH / 16, false, false><<<gg, blk, 0, stream>>>(
        x, W1h, W1l, nullptr, S1, N);
    agg_kernel<DH, true><<<dim3((N + 7) / 8), blk, 0, stream>>>(
        S1, dinv, rowptr, csr_src, csr_coef, b1, Abuf, N);
    // h2 = relu(agg(h1 @ W2) + b2)
    mfma_gemm<DH, DH / 16, false, false><<<gg, blk, 0, stream>>>(
        Abuf, W2h, W2l, nullptr, S1, N);
    agg_kernel<DH, true><<<dim3((N + 7) / 8), blk, 0, stream>>>(
        S1, dinv, rowptr, csr_src, csr_coef, b2, Abuf, N);
    // z = agg(h2 @ W3) + b3
    mfma_gemm<DH, DE / 16, false, false><<<gg, blk, 0, stream>>>(
        Abuf, W3h, W3l, nullptr, S1, N);
    agg_kernel<DE, false><<<dim3((N + 15) / 16), blk, 0, stream>>>(
        S1, dinv, rowptr, csr_src, csr_coef, b3, zout, N);
    // x_hat = relu(z @ Wd1 + bd1) @ Wd2 + bd2
    mfma_gemm<DE, DH / 16, true, true><<<gg, blk, 0, stream>>>(
        zout, Wd1h, Wd1l, bd1, Abuf, N);
    mfma_gemm<DH, DIN / 16, false, true><<<gg, blk, 0, stream>>>(
        Abuf, Wd2h, Wd2l, bd2, xhat, N);
}

// Round 4
// 736.770 us; speedup vs baseline: 1.1132x; 1.1132x over previous
//
#include <hip/hip_runtime.h>

#define DIN 256
#define DH  128
#define DE  64

typedef __attribute__((ext_vector_type(8))) short short8;
typedef __attribute__((ext_vector_type(4))) float f32x4;
typedef __attribute__((ext_vector_type(4))) unsigned short us4;

__device__ inline unsigned short f2bf(float f) {
    unsigned u = __float_as_uint(f);
    return (unsigned short)((u + 0x7FFFu + ((u >> 16) & 1u)) >> 16);
}
__device__ inline float bf2f(unsigned short h) {
    return __uint_as_float((unsigned)h << 16);
}

__device__ inline void gload16(const void* g, void* l) {
    __builtin_amdgcn_global_load_lds(
        (const __attribute__((address_space(1))) void*)g,
        (__attribute__((address_space(3))) void*)l, 16, 0, 0);
}

// ---------------------------------------------------------------- CSR build

__global__ void init_counts_kernel(int* __restrict__ counts, int n) {
    int i = blockIdx.x * blockDim.x + threadIdx.x;
    if (i < n) counts[i] = 0;
}

__global__ void count_edges_kernel(const int* __restrict__ dst,
                                   int* __restrict__ counts, int E) {
    int e = blockIdx.x * blockDim.x + threadIdx.x;
    if (e < E) atomicAdd(&counts[dst[e]], 1);
}

__global__ void dinv_kernel(const int* __restrict__ counts,
                            float* __restrict__ dinv, int n) {
    int i = blockIdx.x * blockDim.x + threadIdx.x;
    if (i < n) dinv[i] = rsqrtf((float)counts[i] + 1.0f);
}

__global__ void scan1_kernel(const int* __restrict__ counts,
                             int* __restrict__ rowptr,
                             int* __restrict__ blocksums, int n) {
    __shared__ int sd[256];
    int t = threadIdx.x;
    int base = blockIdx.x * 1024 + t * 4;
    int v[4];
#pragma unroll
    for (int i = 0; i < 4; i++) v[i] = (base + i < n) ? counts[base + i] : 0;
    int tsum = v[0] + v[1] + v[2] + v[3];
    sd[t] = tsum;
    __syncthreads();
    for (int off = 1; off < 256; off <<= 1) {
        int x = (t >= off) ? sd[t - off] : 0;
        __syncthreads();
        sd[t] += x;
        __syncthreads();
    }
    int p = sd[t] - tsum;
#pragma unroll
    for (int i = 0; i < 4; i++) {
        if (base + i < n) rowptr[base + i] = p;
        p += v[i];
    }
    if (t == 255) blocksums[blockIdx.x] = sd[255];
}

__global__ void scan2_kernel(int* __restrict__ blocksums, int nb) {
    if (threadIdx.x == 0 && blockIdx.x == 0) {
        int run = 0;
        for (int i = 0; i < nb; i++) {
            int x = blocksums[i];
            blocksums[i] = run;
            run += x;
        }
    }
}

__global__ void scan3_kernel(int* __restrict__ rowptr, int* __restrict__ cursor,
                             const int* __restrict__ blocksums, int n, int E) {
    int i = blockIdx.x * blockDim.x + threadIdx.x;
    if (i < n) {
        int r = rowptr[i] + blocksums[i >> 10];
        rowptr[i] = r;
        cursor[i] = r;
    }
    if (i == 0) rowptr[n] = E;
}

__global__ void fill_csr_kernel(const int* __restrict__ src,
                                const int* __restrict__ dst,
                                const float* __restrict__ dinv,
                                int* __restrict__ cursor,
                                int* __restrict__ csr_src,
                                float* __restrict__ csr_coef, int E) {
    int e = blockIdx.x * blockDim.x + threadIdx.x;
    if (e >= E) return;
    int s = src[e], d = dst[e];
    int pos = atomicAdd(&cursor[d], 1);
    csr_src[pos] = s;
    csr_coef[pos] = dinv[s] * dinv[d];
}

// ---------------------------------------------------- weight transpose+split
// W[K][N] fp32  ->  Wh[N][K], Wl[N][K] bf16 (hi + residual-lo)

__global__ void wsplit_kernel(const float* __restrict__ W,
                              unsigned short* __restrict__ Wh,
                              unsigned short* __restrict__ Wl, int K, int N) {
    int i = blockIdx.x * blockDim.x + threadIdx.x;
    if (i >= K * N) return;
    int k = i / N, n = i % N;
    float v = W[i];
    unsigned short h = f2bf(v);
    Wh[(size_t)n * K + k] = h;
    Wl[(size_t)n * K + k] = f2bf(v - bf2f(h));
}

// ------------------------------------------------------- MFMA bf16x3 GEMM
// C[M,N] = A * W (+bias)(+relu), LDS-staged A (bf16 hi/lo), B from L2.
// BM=128, BK=64, 256 thr = 4 waves, wave = 32 rows x CF*16 cols.
// LDS tiles [128 rows][64 k] bf16, 8 x 16B slots/row, slot XOR-swizzled by
// (row&7): pre-swizzled global source + swizzled ds_read (rule 21).
// mfma_f32_16x16x32_bf16: A row=l&15,k=8*(l>>4)+e; B col=l&15,same k;
// D col=l&15,row=4*(l>>4)+e  (verified in round 3).

template <int K, int CF, bool AFP32, bool BIAS, bool RELU, bool SPLIT>
__global__ __launch_bounds__(256, 2) void mfma_gemm(
    const void* __restrict__ Agh, const void* __restrict__ Agl,
    const unsigned short* __restrict__ Wh,
    const unsigned short* __restrict__ Wl, const float* __restrict__ bias,
    float* __restrict__ C, unsigned short* __restrict__ Oh,
    unsigned short* __restrict__ Ol, int M, int NN) {
    __shared__ unsigned short Ath[128 * 64];
    __shared__ unsigned short Atl[128 * 64];

    int t = threadIdx.x;
    int wid = t >> 6;
    int l = t & 63;
    int lr = l & 15, lk = l >> 4;
    int row0 = blockIdx.x * 128;
    int col0 = blockIdx.y * (CF * 16);

    f32x4 acc0[CF], acc1[CF];
#pragma unroll
    for (int j = 0; j < CF; j++) {
        acc0[j] = (f32x4){0.f, 0.f, 0.f, 0.f};
        acc1[j] = (f32x4){0.f, 0.f, 0.f, 0.f};
    }

    for (int c = 0; c < K / 64; ++c) {
        int k0 = c * 64;
        if (AFP32) {
            const float* A = (const float*)Agh;
#pragma unroll
            for (int i = 0; i < 4; i++) {
                int row = i * 32 + (t >> 3);
                int gr = row0 + row;
                if (gr >= M) gr = M - 1;
                int ss = (t & 7) ^ (row & 7);
                const float* sp = A + (size_t)gr * K + k0 + ss * 8;
                float4 f0 = *(const float4*)sp;
                float4 f1 = *(const float4*)(sp + 4);
                float fv[8] = {f0.x, f0.y, f0.z, f0.w,
                               f1.x, f1.y, f1.z, f1.w};
                short8 hv, lv;
#pragma unroll
                for (int e = 0; e < 8; e++) {
                    unsigned short h = f2bf(fv[e]);
                    hv[e] = (short)h;
                    lv[e] = (short)f2bf(fv[e] - bf2f(h));
                }
                int li = (i * 256 + t) * 8;  // == row*64 + (t&7)*8
                *(short8*)&Ath[li] = hv;
                *(short8*)&Atl[li] = lv;
            }
        } else {
            const unsigned short* Ah = (const unsigned short*)Agh;
            const unsigned short* Al = (const unsigned short*)Agl;
#pragma unroll
            for (int i = 0; i < 4; i++) {
                int row = i * 32 + (t >> 3);
                int gr = row0 + row;
                if (gr >= M) gr = M - 1;
                int ss = (t & 7) ^ (row & 7);
                size_t go = (size_t)gr * K + k0 + ss * 8;
                gload16(Ah + go, &Ath[(i * 256 + t) * 8]);
                gload16(Al + go, &Atl[(i * 256 + t) * 8]);
            }
        }
        __syncthreads();

#pragma unroll
        for (int ks = 0; ks < 2; ks++) {
            int r0 = wid * 32 + lr;
            int r1 = r0 + 16;
            int s = ks * 4 + lk;
            short8 a0h = *(const short8*)&Ath[r0 * 64 + (s ^ (r0 & 7)) * 8];
            short8 a0l = *(const short8*)&Atl[r0 * 64 + (s ^ (r0 & 7)) * 8];
            short8 a1h = *(const short8*)&Ath[r1 * 64 + (s ^ (r1 & 7)) * 8];
            short8 a1l = *(const short8*)&Atl[r1 * 64 + (s ^ (r1 & 7)) * 8];
            int kg = k0 + ks * 32 + lk * 8;
#pragma unroll
            for (int j = 0; j < CF; j++) {
                size_t wo = (size_t)(col0 + j * 16 + lr) * K + kg;
                short8 bh = *(const short8*)(Wh + wo);
                short8 bl = *(const short8*)(Wl + wo);
                acc0[j] = __builtin_amdgcn_mfma_f32_16x16x32_bf16(
                    a0h, bh, acc0[j], 0, 0, 0);
                acc0[j] = __builtin_amdgcn_mfma_f32_16x16x32_bf16(
                    a0l, bh, acc0[j], 0, 0, 0);
                acc0[j] = __builtin_amdgcn_mfma_f32_16x16x32_bf16(
                    a0h, bl, acc0[j], 0, 0, 0);
                acc1[j] = __builtin_amdgcn_mfma_f32_16x16x32_bf16(
                    a1h, bh, acc1[j], 0, 0, 0);
                acc1[j] = __builtin_amdgcn_mfma_f32_16x16x32_bf16(
                    a1l, bh, acc1[j], 0, 0, 0);
                acc1[j] = __builtin_amdgcn_mfma_f32_16x16x32_bf16(
                    a1h, bl, acc1[j], 0, 0, 0);
            }
        }
        __syncthreads();
    }

#pragma unroll
    for (int j = 0; j < CF; j++) {
        int col = col0 + j * 16 + lr;
        float bb = BIAS ? bias[col] : 0.f;
#pragma unroll
        for (int e = 0; e < 4; e++) {
            int r = row0 + wid * 32 + lk * 4 + e;
#pragma unroll
            for (int rf = 0; rf < 2; rf++) {
                int rr = r + rf * 16;
                if (rr >= M) continue;
                float v = (rf ? acc1[j][e] : acc0[j][e]) + bb;
                if (RELU) v = fmaxf(v, 0.f);
                if (SPLIT) {
                    unsigned short h = f2bf(v);
                    Oh[(size_t)rr * NN + col] = h;
                    Ol[(size_t)rr * NN + col] = f2bf(v - bf2f(h));
                } else {
                    C[(size_t)rr * NN + col] = v;
                }
            }
        }
    }
}

// ------------------------------------------------------------- aggregation
// out[v] = sum_{e: dst==v} h[src_e]*coef_e + h[v]*dinv[v]^2 + bias (, relu)
// TPN = D/16 lanes/node, each lane owns 4 float4 chunks -> 8 gathers in
// flight per 2-edge step. Writes bf16 hi/lo (GEMM-A form) + optional fp32.

template <int D, bool RELU, bool WF32>
__global__ __launch_bounds__(256) void agg_kernel(
    const float* __restrict__ h, const float* __restrict__ dinv,
    const int* __restrict__ rowptr, const int* __restrict__ csr_src,
    const float* __restrict__ csr_coef, const float* __restrict__ bias,
    unsigned short* __restrict__ outh, unsigned short* __restrict__ outl,
    float* __restrict__ outf, int n) {
    constexpr int TPN = D / 16;
    constexpr int NPB = 256 / TPN;
    int v = blockIdx.x * NPB + threadIdx.x / TPN;
    int d = threadIdx.x % TPN;
    if (v >= n) return;

    float di = dinv[v];
    float s2 = di * di;
    const float* hv = h + (size_t)v * D + d * 4;
    float4 acc[4];
#pragma unroll
    for (int i = 0; i < 4; i++) {
        float4 sv = *(const float4*)(hv + i * TPN * 4);
        float4 bv = *(const float4*)&bias[(i * TPN + d) * 4];
        acc[i].x = fmaf(sv.x, s2, bv.x);
        acc[i].y = fmaf(sv.y, s2, bv.y);
        acc[i].z = fmaf(sv.z, s2, bv.z);
        acc[i].w = fmaf(sv.w, s2, bv.w);
    }

    int e0 = rowptr[v], e1 = rowptr[v + 1];
    int e = e0;
    for (; e + 2 <= e1; e += 2) {
        int s0 = csr_src[e], s1 = csr_src[e + 1];
        float c0 = csr_coef[e], c1 = csr_coef[e + 1];
        const float* p0 = h + (size_t)s0 * D + d * 4;
        const float* p1 = h + (size_t)s1 * D + d * 4;
        float4 g0[4], g1[4];
#pragma unroll
        for (int i = 0; i < 4; i++) g0[i] = *(const float4*)(p0 + i * TPN * 4);
#pragma unroll
        for (int i = 0; i < 4; i++) g1[i] = *(const float4*)(p1 + i * TPN * 4);
#pragma unroll
        for (int i = 0; i < 4; i++) {
            acc[i].x = fmaf(g0[i].x, c0, acc[i].x);
            acc[i].y = fmaf(g0[i].y, c0, acc[i].y);
            acc[i].z = fmaf(g0[i].z, c0, acc[i].z);
            acc[i].w = fmaf(g0[i].w, c0, acc[i].w);
            acc[i].x = fmaf(g1[i].x, c1, acc[i].x);
            acc[i].y = fmaf(g1[i].y, c1, acc[i].y);
            acc[i].z = fmaf(g1[i].z, c1, acc[i].z);
            acc[i].w = fmaf(g1[i].w, c1, acc[i].w);
        }
    }
    if (e < e1) {
        int s0 = csr_src[e];
        float c0 = csr_coef[e];
        const float* p0 = h + (size_t)s0 * D + d * 4;
#pragma unroll
        for (int i = 0; i < 4; i++) {
            float4 g = *(const float4*)(p0 + i * TPN * 4);
            acc[i].x = fmaf(g.x, c0, acc[i].x);
            acc[i].y = fmaf(g.y, c0, acc[i].y);
            acc[i].z = fmaf(g.z, c0, acc[i].z);
            acc[i].w = fmaf(g.w, c0, acc[i].w);
        }
    }

#pragma unroll
    for (int i = 0; i < 4; i++) {
        if (RELU) {
            acc[i].x = fmaxf(acc[i].x, 0.f);
            acc[i].y = fmaxf(acc[i].y, 0.f);
            acc[i].z = fmaxf(acc[i].z, 0.f);
            acc[i].w = fmaxf(acc[i].w, 0.f);
        }
        size_t o = (size_t)v * D + (i * TPN + d) * 4;
        float av[4] = {acc[i].x, acc[i].y, acc[i].z, acc[i].w};
        us4 hw, lw;
#pragma unroll
        for (int q = 0; q < 4; q++) {
            unsigned short hh = f2bf(av[q]);
            hw[q] = hh;
            lw[q] = f2bf(av[q] - bf2f(hh));
        }
        *(us4*)&outh[o] = hw;
        *(us4*)&outl[o] = lw;
        if (WF32) *(float4*)&outf[o] = acc[i];
    }
}

// ---------------------------------------------------------------- launcher

extern "C" void kernel_launch(void* const* d_in, const int* in_sizes, int n_in,
                              void* d_out, int out_size, void* d_ws,
                              size_t ws_size, hipStream_t stream) {
    const float* x   = (const float*)d_in[0];
    const int*   ei  = (const int*)d_in[1];
    const float* W1  = (const float*)d_in[2];
    const float* b1  = (const float*)d_in[3];
    const float* W2  = (const float*)d_in[4];
    const float* b2  = (const float*)d_in[5];
    const float* W3  = (const float*)d_in[6];
    const float* b3  = (const float*)d_in[7];
    const float* Wd1 = (const float*)d_in[8];
    const float* bd1 = (const float*)d_in[9];
    const float* Wd2 = (const float*)d_in[10];
    const float* bd2 = (const float*)d_in[11];

    const int N = in_sizes[0] / DIN;
    const int E = in_sizes[1] / 2;
    const int* src = ei;
    const int* dst = ei + E;

    char* w = (char*)d_ws;
    auto alloc = [&](size_t bytes) -> char* {
        char* p = w;
        w += (bytes + 255) & ~(size_t)255;
        return p;
    };
    int*   counts    = (int*)alloc((size_t)N * 4);
    float* dinv      = (float*)alloc((size_t)N * 4);
    int*   rowptr    = (int*)alloc((size_t)(N + 1) * 4);
    int*   cursor    = (int*)alloc((size_t)N * 4);
    int*   blocksums = (int*)alloc(4096);
    int*   csr_src   = (int*)alloc((size_t)E * 4);
    float* csr_coef  = (float*)alloc((size_t)E * 4);
    unsigned short* hh = (unsigned short*)alloc((size_t)N * DH * 2);
    unsigned short* hl = (unsigned short*)alloc((size_t)N * DH * 2);
    unsigned short* W1h  = (unsigned short*)alloc(DIN * DH * 2);
    unsigned short* W1l  = (unsigned short*)alloc(DIN * DH * 2);
    unsigned short* W2h  = (unsigned short*)alloc(DH * DH * 2);
    unsigned short* W2l  = (unsigned short*)alloc(DH * DH * 2);
    unsigned short* W3h  = (unsigned short*)alloc(DH * DE * 2);
    unsigned short* W3l  = (unsigned short*)alloc(DH * DE * 2);
    unsigned short* Wd1h = (unsigned short*)alloc(DE * DH * 2);
    unsigned short* Wd1l = (unsigned short*)alloc(DE * DH * 2);
    unsigned short* Wd2h = (unsigned short*)alloc(DH * DIN * 2);
    unsigned short* Wd2l = (unsigned short*)alloc(DH * DIN * 2);

    float* zout = (float*)d_out;               // [N, 64]
    float* xhat = zout + (size_t)N * DE;       // [N, 256]
    float* S1   = xhat;                        // [N,128] scratch in xhat
    // z hi/lo parked in upper half of xhat region (dead until G5 rewrites)
    unsigned short* zh = (unsigned short*)(xhat + (size_t)N * DH);
    unsigned short* zl = zh + (size_t)N * DE;
    // r (decoder hidden) hi/lo reuse the hh/hl ws buffers (h2 dead by then)
    unsigned short* rh = hh;
    unsigned short* rl = hl;

    dim3 blk(256);
    int gN = (N + 255) / 256, gE = (E + 255) / 256;

    init_counts_kernel<<<gN, blk, 0, stream>>>(counts, N);
    count_edges_kernel<<<gE, blk, 0, stream>>>(dst, counts, E);
    dinv_kernel<<<gN, blk, 0, stream>>>(counts, dinv, N);
    int nb = (N + 1023) / 1024;
    scan1_kernel<<<nb, blk, 0, stream>>>(counts, rowptr, blocksums, N);
    scan2_kernel<<<1, 64, 0, stream>>>(blocksums, nb);
    scan3_kernel<<<gN, blk, 0, stream>>>(rowptr, cursor, blocksums, N, E);
    fill_csr_kernel<<<gE, blk, 0, stream>>>(src, dst, dinv, cursor, csr_src,
                                            csr_coef, E);

    wsplit_kernel<<<(DIN * DH + 255) / 256, blk, 0, stream>>>(W1, W1h, W1l,
                                                              DIN, DH);
    wsplit_kernel<<<(DH * DH + 255) / 256, blk, 0, stream>>>(W2, W2h, W2l,
                                                             DH, DH);
    wsplit_kernel<<<(DH * DE + 255) / 256, blk, 0, stream>>>(W3, W3h, W3l,
                                                             DH, DE);
    wsplit_kernel<<<(DE * DH + 255) / 256, blk, 0, stream>>>(Wd1, Wd1h, Wd1l,
                                                             DE, DH);
    wsplit_kernel<<<(DH * DIN + 255) / 256, blk, 0, stream>>>(Wd2, Wd2h, Wd2l,
                                                              DH, DIN);

    int gm = (N + 127) / 128;

    // h1 = relu(agg(x @ W1) + b1)   (G1 reg-stages fp32 x -> bf16 hi/lo)
    mfma_gemm<DIN, 8, true, false, false, false><<<dim3(gm, 1), blk, 0,
        stream>>>(x, nullptr, W1h, W1l, nullptr, S1, nullptr, nullptr, N, DH);
    agg_kernel<DH, true, false><<<(N + 31) / 32, blk, 0, stream>>>(
        S1, dinv, rowptr, csr_src, csr_coef, b1, hh, hl, nullptr, N);
    // h2 = relu(agg(h1 @ W2) + b2)
    mfma_gemm<DH, 8, false, false, false, false><<<dim3(gm, 1), blk, 0,
        stream>>>(hh, hl, W2h, W2l, nullptr, S1, nullptr, nullptr, N, DH);
    agg_kernel<DH, true, false><<<(N + 31) / 32, blk, 0, stream>>>(
        S1, dinv, rowptr, csr_src, csr_coef, b2, hh, hl, nullptr, N);
    // z = agg(h2 @ W3) + b3
    mfma_gemm<DH, 4, false, false, false, false><<<dim3(gm, 1), blk, 0,
        stream>>>(hh, hl, W3h, W3l, nullptr, S1, nullptr, nullptr, N, DE);
    agg_kernel<DE, false, true><<<(N + 63) / 64, blk, 0, stream>>>(
        S1, dinv, rowptr, csr_src, csr_coef, b3, zh, zl, zout, N);
    // r = relu(z @ Wd1 + bd1)  -> bf16 hi/lo directly
    mfma_gemm<DE, 8, false, true, true, true><<<dim3(gm, 1), blk, 0,
        stream>>>(zh, zl, Wd1h, Wd1l, bd1, nullptr, rh, rl, N, DH);
    // x_hat = r @ Wd2 + bd2
    mfma_gemm<DH, 8, false, true, false, false><<<dim3(gm, 2), blk, 0,
        stream>>>(rh, rl, Wd2h, Wd2l, bd2, xhat, nullptr, nullptr, N, DIN);
}

// Round 5
// 600.464 us; speedup vs baseline: 1.3659x; 1.2270x over previous
//
#include <hip/hip_runtime.h>

#define DIN 256
#define DH  128
#define DE  64

typedef __attribute__((ext_vector_type(8))) short short8;
typedef __attribute__((ext_vector_type(4))) float f32x4;
typedef __attribute__((ext_vector_type(4))) unsigned short us4;

__device__ inline unsigned short f2bf(float f) {
    unsigned u = __float_as_uint(f);
    return (unsigned short)((u + 0x7FFFu + ((u >> 16) & 1u)) >> 16);
}
__device__ inline float bf2f(unsigned short h) {
    return __uint_as_float((unsigned)h << 16);
}

__device__ inline void gload16(const void* g, void* l) {
    __builtin_amdgcn_global_load_lds(
        (const __attribute__((address_space(1))) void*)g,
        (__attribute__((address_space(3))) void*)l, 16, 0, 0);
}

// ---------------------------------------------------------------- CSR build

__global__ void init_counts_kernel(int* __restrict__ counts, int n) {
    int i = blockIdx.x * blockDim.x + threadIdx.x;
    if (i < n) counts[i] = 0;
}

__global__ void count_edges_kernel(const int* __restrict__ dst,
                                   int* __restrict__ counts, int E) {
    int e = blockIdx.x * blockDim.x + threadIdx.x;
    if (e < E) atomicAdd(&counts[dst[e]], 1);
}

__global__ void dinv_kernel(const int* __restrict__ counts,
                            float* __restrict__ dinv, int n) {
    int i = blockIdx.x * blockDim.x + threadIdx.x;
    if (i < n) dinv[i] = rsqrtf((float)counts[i] + 1.0f);
}

__global__ void scan1_kernel(const int* __restrict__ counts,
                             int* __restrict__ rowptr,
                             int* __restrict__ blocksums, int n) {
    __shared__ int sd[256];
    int t = threadIdx.x;
    int base = blockIdx.x * 1024 + t * 4;
    int v[4];
#pragma unroll
    for (int i = 0; i < 4; i++) v[i] = (base + i < n) ? counts[base + i] : 0;
    int tsum = v[0] + v[1] + v[2] + v[3];
    sd[t] = tsum;
    __syncthreads();
    for (int off = 1; off < 256; off <<= 1) {
        int x = (t >= off) ? sd[t - off] : 0;
        __syncthreads();
        sd[t] += x;
        __syncthreads();
    }
    int p = sd[t] - tsum;
#pragma unroll
    for (int i = 0; i < 4; i++) {
        if (base + i < n) rowptr[base + i] = p;
        p += v[i];
    }
    if (t == 255) blocksums[blockIdx.x] = sd[255];
}

__global__ void scan2_kernel(int* __restrict__ blocksums, int nb) {
    if (threadIdx.x == 0 && blockIdx.x == 0) {
        int run = 0;
        for (int i = 0; i < nb; i++) {
            int x = blocksums[i];
            blocksums[i] = run;
            run += x;
        }
    }
}

__global__ void scan3_kernel(int* __restrict__ rowptr, int* __restrict__ cursor,
                             const int* __restrict__ blocksums, int n, int E) {
    int i = blockIdx.x * blockDim.x + threadIdx.x;
    if (i < n) {
        int r = rowptr[i] + blocksums[i >> 10];
        rowptr[i] = r;
        cursor[i] = r;
    }
    if (i == 0) rowptr[n] = E;
}

__global__ void fill_csr_kernel(const int* __restrict__ src,
                                const int* __restrict__ dst,
                                const float* __restrict__ dinv,
                                int* __restrict__ cursor,
                                int* __restrict__ csr_src,
                                float* __restrict__ csr_coef, int E) {
    int e = blockIdx.x * blockDim.x + threadIdx.x;
    if (e >= E) return;
    int s = src[e], d = dst[e];
    int pos = atomicAdd(&cursor[d], 1);
    csr_src[pos] = s;
    csr_coef[pos] = dinv[s] * dinv[d];
}

// ------------------------------------------------- weight split + LDS-tile
// W[K][N] fp32 -> WtH/WtL bf16 arranged EXACTLY in the GEMM's B-LDS layout:
// tile (cb, chunk) holds CF16 cols x 64 k; element (c_local, kk) at
// c_local*64 + ((kk/8) ^ (c_local&7))*8 + kk%8  (XOR-swizzle pre-applied so
// global_load_lds stages linearly and ds_read_b128 un-swizzles — rule 21).

__global__ void wtile_kernel(const float* __restrict__ W,
                             unsigned short* __restrict__ WtH,
                             unsigned short* __restrict__ WtL, int K, int N,
                             int CF16) {
    int i = blockIdx.x * blockDim.x + threadIdx.x;
    if (i >= K * N) return;
    int k = i / N, n = i % N;
    float v = W[i];
    unsigned short h = f2bf(v);
    unsigned short lo = f2bf(v - bf2f(h));
    int cb = n / CF16, cl = n % CF16;
    int chunk = k >> 6, kk = k & 63;
    int s = kk >> 3, e = kk & 7;
    size_t idx = (size_t)(cb * (K >> 6) + chunk) * (CF16 * 64) + cl * 64 +
                 ((s ^ (cl & 7)) * 8) + e;
    WtH[idx] = h;
    WtL[idx] = lo;
}

// ------------------------------------------------------- MFMA bf16x3 GEMM
// C[M,N] = A * W (+bias)(+relu). BM=128, BK=64, 4 waves, wave = 32 rows x
// CF*16 cols. BOTH operands LDS-staged (A: swizzled-source global_load_lds;
// B: pre-tiled swizzled weights, linear global_load_lds). Inner loop is
// ds_read_b128 + MFMA only. mfma_f32_16x16x32_bf16: A row=l&15,k=8*(l>>4)+e;
// B col=l&15; D col=l&15,row=4*(l>>4)+e (verified round 3/4).

template <int K, int CF, bool AFP32, bool BIAS, bool RELU, bool SPLIT>
__global__ __launch_bounds__(256, 2) void mfma_gemm(
    const void* __restrict__ Agh, const void* __restrict__ Agl,
    const unsigned short* __restrict__ WtH,
    const unsigned short* __restrict__ WtL, const float* __restrict__ bias,
    float* __restrict__ C, unsigned short* __restrict__ Oh,
    unsigned short* __restrict__ Ol, int M, int NN) {
    constexpr int CF16 = CF * 16;
    constexpr int CHUNKS = K / 64;
    __shared__ unsigned short Ath[128 * 64];
    __shared__ unsigned short Atl[128 * 64];
    __shared__ unsigned short Bth[CF16 * 64];
    __shared__ unsigned short Btl[CF16 * 64];

    int t = threadIdx.x;
    int wid = t >> 6;
    int l = t & 63;
    int lr = l & 15, lk = l >> 4;
    int row0 = blockIdx.x * 128;
    int col0 = blockIdx.y * CF16;

    f32x4 acc0[CF], acc1[CF];
#pragma unroll
    for (int j = 0; j < CF; j++) {
        acc0[j] = (f32x4){0.f, 0.f, 0.f, 0.f};
        acc1[j] = (f32x4){0.f, 0.f, 0.f, 0.f};
    }

    for (int c = 0; c < CHUNKS; ++c) {
        int k0 = c * 64;
        // ---- stage B tile (pre-swizzled, contiguous): no VGPR round-trip
        size_t bbase = (size_t)(blockIdx.y * CHUNKS + c) * (CF16 * 64);
#pragma unroll
        for (int i = 0; i < CF16 / 32; i++) {
            int idx = (i * 256 + t) * 8;
            gload16(WtH + bbase + idx, &Bth[idx]);
            gload16(WtL + bbase + idx, &Btl[idx]);
        }
        // ---- stage A tile
        if (AFP32) {
            const float* A = (const float*)Agh;
#pragma unroll
            for (int i = 0; i < 4; i++) {
                int row = i * 32 + (t >> 3);
                int gr = row0 + row;
                if (gr >= M) gr = M - 1;
                int ss = (t & 7) ^ (row & 7);
                const float* sp = A + (size_t)gr * K + k0 + ss * 8;
                float4 f0 = *(const float4*)sp;
                float4 f1 = *(const float4*)(sp + 4);
                float fv[8] = {f0.x, f0.y, f0.z, f0.w,
                               f1.x, f1.y, f1.z, f1.w};
                short8 hv, lv;
#pragma unroll
                for (int e = 0; e < 8; e++) {
                    unsigned short h = f2bf(fv[e]);
                    hv[e] = (short)h;
                    lv[e] = (short)f2bf(fv[e] - bf2f(h));
                }
                int li = (i * 256 + t) * 8;  // == row*64 + (t&7)*8
                *(short8*)&Ath[li] = hv;
                *(short8*)&Atl[li] = lv;
            }
        } else {
            const unsigned short* Ah = (const unsigned short*)Agh;
            const unsigned short* Al = (const unsigned short*)Agl;
#pragma unroll
            for (int i = 0; i < 4; i++) {
                int row = i * 32 + (t >> 3);
                int gr = row0 + row;
                if (gr >= M) gr = M - 1;
                int ss = (t & 7) ^ (row & 7);
                size_t go = (size_t)gr * K + k0 + ss * 8;
                gload16(Ah + go, &Ath[(i * 256 + t) * 8]);
                gload16(Al + go, &Atl[(i * 256 + t) * 8]);
            }
        }
        __syncthreads();

#pragma unroll
        for (int ks = 0; ks < 2; ks++) {
            int r0 = wid * 32 + lr;
            int r1 = r0 + 16;
            int s = ks * 4 + lk;
            short8 a0h = *(const short8*)&Ath[r0 * 64 + (s ^ (r0 & 7)) * 8];
            short8 a0l = *(const short8*)&Atl[r0 * 64 + (s ^ (r0 & 7)) * 8];
            short8 a1h = *(const short8*)&Ath[r1 * 64 + (s ^ (r1 & 7)) * 8];
            short8 a1l = *(const short8*)&Atl[r1 * 64 + (s ^ (r1 & 7)) * 8];
#pragma unroll
            for (int j = 0; j < CF; j++) {
                int bo = (j * 16 + lr) * 64 + ((s ^ (lr & 7)) * 8);
                short8 bh = *(const short8*)&Bth[bo];
                short8 bl = *(const short8*)&Btl[bo];
                acc0[j] = __builtin_amdgcn_mfma_f32_16x16x32_bf16(
                    a0h, bh, acc0[j], 0, 0, 0);
                acc0[j] = __builtin_amdgcn_mfma_f32_16x16x32_bf16(
                    a0l, bh, acc0[j], 0, 0, 0);
                acc0[j] = __builtin_amdgcn_mfma_f32_16x16x32_bf16(
                    a0h, bl, acc0[j], 0, 0, 0);
                acc1[j] = __builtin_amdgcn_mfma_f32_16x16x32_bf16(
                    a1h, bh, acc1[j], 0, 0, 0);
                acc1[j] = __builtin_amdgcn_mfma_f32_16x16x32_bf16(
                    a1l, bh, acc1[j], 0, 0, 0);
                acc1[j] = __builtin_amdgcn_mfma_f32_16x16x32_bf16(
                    a1h, bl, acc1[j], 0, 0, 0);
            }
        }
        __syncthreads();
    }

#pragma unroll
    for (int j = 0; j < CF; j++) {
        int col = col0 + j * 16 + lr;
        float bb = BIAS ? bias[col] : 0.f;
#pragma unroll
        for (int e = 0; e < 4; e++) {
            int r = row0 + wid * 32 + lk * 4 + e;
#pragma unroll
            for (int rf = 0; rf < 2; rf++) {
                int rr = r + rf * 16;
                if (rr >= M) continue;
                float v = (rf ? acc1[j][e] : acc0[j][e]) + bb;
                if (RELU) v = fmaxf(v, 0.f);
                if (SPLIT) {
                    unsigned short h = f2bf(v);
                    Oh[(size_t)rr * NN + col] = h;
                    Ol[(size_t)rr * NN + col] = f2bf(v - bf2f(h));
                } else {
                    C[(size_t)rr * NN + col] = v;
                }
            }
        }
    }
}

// ------------------------------------------------------------- aggregation
// out[v] = sum_{e: dst==v} h[src_e]*coef_e + h[v]*dinv[v]^2 + bias (, relu)
// TPN = D/16 lanes/node, each lane owns 4 float4 chunks -> 8 gathers in
// flight per 2-edge step. Writes bf16 hi/lo (GEMM-A form) + optional fp32.

template <int D, bool RELU, bool WF32>
__global__ __launch_bounds__(256) void agg_kernel(
    const float* __restrict__ h, const float* __restrict__ dinv,
    const int* __restrict__ rowptr, const int* __restrict__ csr_src,
    const float* __restrict__ csr_coef, const float* __restrict__ bias,
    unsigned short* __restrict__ outh, unsigned short* __restrict__ outl,
    float* __restrict__ outf, int n) {
    constexpr int TPN = D / 16;
    constexpr int NPB = 256 / TPN;
    int v = blockIdx.x * NPB + threadIdx.x / TPN;
    int d = threadIdx.x % TPN;
    if (v >= n) return;

    float di = dinv[v];
    float s2 = di * di;
    const float* hv = h + (size_t)v * D + d * 4;
    float4 acc[4];
#pragma unroll
    for (int i = 0; i < 4; i++) {
        float4 sv = *(const float4*)(hv + i * TPN * 4);
        float4 bv = *(const float4*)&bias[(i * TPN + d) * 4];
        acc[i].x = fmaf(sv.x, s2, bv.x);
        acc[i].y = fmaf(sv.y, s2, bv.y);
        acc[i].z = fmaf(sv.z, s2, bv.z);
        acc[i].w = fmaf(sv.w, s2, bv.w);
    }

    int e0 = rowptr[v], e1 = rowptr[v + 1];
    int e = e0;
    for (; e + 2 <= e1; e += 2) {
        int s0 = csr_src[e], s1 = csr_src[e + 1];
        float c0 = csr_coef[e], c1 = csr_coef[e + 1];
        const float* p0 = h + (size_t)s0 * D + d * 4;
        const float* p1 = h + (size_t)s1 * D + d * 4;
        float4 g0[4], g1[4];
#pragma unroll
        for (int i = 0; i < 4; i++) g0[i] = *(const float4*)(p0 + i * TPN * 4);
#pragma unroll
        for (int i = 0; i < 4; i++) g1[i] = *(const float4*)(p1 + i * TPN * 4);
#pragma unroll
        for (int i = 0; i < 4; i++) {
            acc[i].x = fmaf(g0[i].x, c0, acc[i].x);
            acc[i].y = fmaf(g0[i].y, c0, acc[i].y);
            acc[i].z = fmaf(g0[i].z, c0, acc[i].z);
            acc[i].w = fmaf(g0[i].w, c0, acc[i].w);
            acc[i].x = fmaf(g1[i].x, c1, acc[i].x);
            acc[i].y = fmaf(g1[i].y, c1, acc[i].y);
            acc[i].z = fmaf(g1[i].z, c1, acc[i].z);
            acc[i].w = fmaf(g1[i].w, c1, acc[i].w);
        }
    }
    if (e < e1) {
        int s0 = csr_src[e];
        float c0 = csr_coef[e];
        const float* p0 = h + (size_t)s0 * D + d * 4;
#pragma unroll
        for (int i = 0; i < 4; i++) {
            float4 g = *(const float4*)(p0 + i * TPN * 4);
            acc[i].x = fmaf(g.x, c0, acc[i].x);
            acc[i].y = fmaf(g.y, c0, acc[i].y);
            acc[i].z = fmaf(g.z, c0, acc[i].z);
            acc[i].w = fmaf(g.w, c0, acc[i].w);
        }
    }

#pragma unroll
    for (int i = 0; i < 4; i++) {
        if (RELU) {
            acc[i].x = fmaxf(acc[i].x, 0.f);
            acc[i].y = fmaxf(acc[i].y, 0.f);
            acc[i].z = fmaxf(acc[i].z, 0.f);
            acc[i].w = fmaxf(acc[i].w, 0.f);
        }
        size_t o = (size_t)v * D + (i * TPN + d) * 4;
        float av[4] = {acc[i].x, acc[i].y, acc[i].z, acc[i].w};
        us4 hw, lw;
#pragma unroll
        for (int q = 0; q < 4; q++) {
            unsigned short hh = f2bf(av[q]);
            hw[q] = hh;
            lw[q] = f2bf(av[q] - bf2f(hh));
        }
        *(us4*)&outh[o] = hw;
        *(us4*)&outl[o] = lw;
        if (WF32) *(float4*)&outf[o] = acc[i];
    }
}

// ---------------------------------------------------------------- launcher

extern "C" void kernel_launch(void* const* d_in, const int* in_sizes, int n_in,
                              void* d_out, int out_size, void* d_ws,
                              size_t ws_size, hipStream_t stream) {
    const float* x   = (const float*)d_in[0];
    const int*   ei  = (const int*)d_in[1];
    const float* W1  = (const float*)d_in[2];
    const float* b1  = (const float*)d_in[3];
    const float* W2  = (const float*)d_in[4];
    const float* b2  = (const float*)d_in[5];
    const float* W3  = (const float*)d_in[6];
    const float* b3  = (const float*)d_in[7];
    const float* Wd1 = (const float*)d_in[8];
    const float* bd1 = (const float*)d_in[9];
    const float* Wd2 = (const float*)d_in[10];
    const float* bd2 = (const float*)d_in[11];

    const int N = in_sizes[0] / DIN;
    const int E = in_sizes[1] / 2;
    const int* src = ei;
    const int* dst = ei + E;

    char* w = (char*)d_ws;
    auto alloc = [&](size_t bytes) -> char* {
        char* p = w;
        w += (bytes + 255) & ~(size_t)255;
        return p;
    };
    int*   counts    = (int*)alloc((size_t)N * 4);
    float* dinv      = (float*)alloc((size_t)N * 4);
    int*   rowptr    = (int*)alloc((size_t)(N + 1) * 4);
    int*   cursor    = (int*)alloc((size_t)N * 4);
    int*   blocksums = (int*)alloc(4096);
    int*   csr_src   = (int*)alloc((size_t)E * 4);
    float* csr_coef  = (float*)alloc((size_t)E * 4);
    unsigned short* hh = (unsigned short*)alloc((size_t)N * DH * 2);
    unsigned short* hl = (unsigned short*)alloc((size_t)N * DH * 2);
    unsigned short* W1h  = (unsigned short*)alloc(DIN * DH * 2);
    unsigned short* W1l  = (unsigned short*)alloc(DIN * DH * 2);
    unsigned short* W2h  = (unsigned short*)alloc(DH * DH * 2);
    unsigned short* W2l  = (unsigned short*)alloc(DH * DH * 2);
    unsigned short* W3h  = (unsigned short*)alloc(DH * DE * 2);
    unsigned short* W3l  = (unsigned short*)alloc(DH * DE * 2);
    unsigned short* Wd1h = (unsigned short*)alloc(DE * DH * 2);
    unsigned short* Wd1l = (unsigned short*)alloc(DE * DH * 2);
    unsigned short* Wd2h = (unsigned short*)alloc(DH * DIN * 2);
    unsigned short* Wd2l = (unsigned short*)alloc(DH * DIN * 2);

    float* zout = (float*)d_out;               // [N, 64]
    float* xhat = zout + (size_t)N * DE;       // [N, 256]
    float* S1   = xhat;                        // [N,128] scratch in xhat
    unsigned short* zh = (unsigned short*)(xhat + (size_t)N * DH);
    unsigned short* zl = zh + (size_t)N * DE;
    unsigned short* rh = hh;
    unsigned short* rl = hl;

    dim3 blk(256);
    int gN = (N + 255) / 256, gE = (E + 255) / 256;

    init_counts_kernel<<<gN, blk, 0, stream>>>(counts, N);
    count_edges_kernel<<<gE, blk, 0, stream>>>(dst, counts, E);
    dinv_kernel<<<gN, blk, 0, stream>>>(counts, dinv, N);
    int nb = (N + 1023) / 1024;
    scan1_kernel<<<nb, blk, 0, stream>>>(counts, rowptr, blocksums, N);
    scan2_kernel<<<1, 64, 0, stream>>>(blocksums, nb);
    scan3_kernel<<<gN, blk, 0, stream>>>(rowptr, cursor, blocksums, N, E);
    fill_csr_kernel<<<gE, blk, 0, stream>>>(src, dst, dinv, cursor, csr_src,
                                            csr_coef, E);

    // weight split into pre-swizzled B-LDS tile layouts
    wtile_kernel<<<(DIN * DH + 255) / 256, blk, 0, stream>>>(W1, W1h, W1l,
                                                             DIN, DH, 128);
    wtile_kernel<<<(DH * DH + 255) / 256, blk, 0, stream>>>(W2, W2h, W2l,
                                                            DH, DH, 128);
    wtile_kernel<<<(DH * DE + 255) / 256, blk, 0, stream>>>(W3, W3h, W3l,
                                                            DH, DE, 64);
    wtile_kernel<<<(DE * DH + 255) / 256, blk, 0, stream>>>(Wd1, Wd1h, Wd1l,
                                                            DE, DH, 128);
    wtile_kernel<<<(DH * DIN + 255) / 256, blk, 0, stream>>>(Wd2, Wd2h, Wd2l,
                                                             DH, DIN, 128);

    int gm = (N + 127) / 128;

    // h1 = relu(agg(x @ W1) + b1)   (G1 reg-stages fp32 x -> bf16 hi/lo)
    mfma_gemm<DIN, 8, true, false, false, false><<<dim3(gm, 1), blk, 0,
        stream>>>(x, nullptr, W1h, W1l, nullptr, S1, nullptr, nullptr, N, DH);
    agg_kernel<DH, true, false><<<(N + 31) / 32, blk, 0, stream>>>(
        S1, dinv, rowptr, csr_src, csr_coef, b1, hh, hl, nullptr, N);
    // h2 = relu(agg(h1 @ W2) + b2)
    mfma_gemm<DH, 8, false, false, false, false><<<dim3(gm, 1), blk, 0,
        stream>>>(hh, hl, W2h, W2l, nullptr, S1, nullptr, nullptr, N, DH);
    agg_kernel<DH, true, false><<<(N + 31) / 32, blk, 0, stream>>>(
        S1, dinv, rowptr, csr_src, csr_coef, b2, hh, hl, nullptr, N);
    // z = agg(h2 @ W3) + b3
    mfma_gemm<DH, 4, false, false, false, false><<<dim3(gm, 1), blk, 0,
        stream>>>(hh, hl, W3h, W3l, nullptr, S1, nullptr, nullptr, N, DE);
    agg_kernel<DE, false, true><<<(N + 63) / 64, blk, 0, stream>>>(
        S1, dinv, rowptr, csr_src, csr_coef, b3, zh, zl, zout, N);
    // r = relu(z @ Wd1 + bd1)  -> bf16 hi/lo directly
    mfma_gemm<DE, 8, false, true, true, true><<<dim3(gm, 1), blk, 0,
        stream>>>(zh, zl, Wd1h, Wd1l, bd1, nullptr, rh, rl, N, DH);
    // x_hat = r @ Wd2 + bd2
    mfma_gemm<DH, 8, false, true, false, false><<<dim3(gm, 2), blk, 0,
        stream>>>(rh, rl, Wd2h, Wd2l, bd2, xhat, nullptr, nullptr, N, DIN);
}